// Round 12
// baseline (301.792 us; speedup 1.0000x reference)
//
#include <hip/hip_runtime.h>

#define EPS 1e-5f

typedef float v4f __attribute__((ext_vector_type(4)));

// ---------------- K1: red[o][pix] = sum_c x[b,c,hw] * Wr[o,c]  (+ stats partials)
// grid 512 = 8 oGroups(6 o each) x 64 pixBlocks, block 256
__global__ __launch_bounds__(256) void k_reduce_conv(
    const float* __restrict__ x, const float* __restrict__ Wr,
    float* __restrict__ red, float* __restrict__ spart)
{
  int ob = blockIdx.x >> 6;           // 0..7
  int pb = blockIdx.x & 63;           // 0..63
  int o0 = ob * 6;
  int pix = (pb << 8) + threadIdx.x;  // 0..16383
  int b = pix >> 10;
  int hw = pix & 1023;
  const float* xp = x + ((size_t)b * 192) * 1024 + hw;
  float acc[6] = {0.f, 0.f, 0.f, 0.f, 0.f, 0.f};
  for (int c = 0; c < 192; ++c) {
    float xv = xp[(size_t)c * 1024];
#pragma unroll
    for (int j = 0; j < 6; ++j)
      acc[j] = fmaf(xv, Wr[(o0 + j) * 192 + c], acc[j]);
  }
#pragma unroll
  for (int j = 0; j < 6; ++j)
    red[(size_t)(o0 + j) * 16384 + pix] = acc[j];

  // per-block sum / sumsq partials for BN stats
  int t = threadIdx.x, lane = t & 63, wid = t >> 6;
  float sv[6], qv[6];
#pragma unroll
  for (int j = 0; j < 6; ++j) { sv[j] = acc[j]; qv[j] = acc[j] * acc[j]; }
#pragma unroll
  for (int off = 32; off > 0; off >>= 1)
#pragma unroll
    for (int j = 0; j < 6; ++j) {
      sv[j] += __shfl_down(sv[j], off);
      qv[j] += __shfl_down(qv[j], off);
    }
  __shared__ float ps[4][12];
  if (lane == 0)
#pragma unroll
    for (int j = 0; j < 6; ++j) { ps[wid][j] = sv[j]; ps[wid][6 + j] = qv[j]; }
  __syncthreads();
  if (t < 12) {
    float v = ps[0][t] + ps[1][t] + ps[2][t] + ps[3][t];
    int j = t % 6, s = t / 6;
    spart[(size_t)(s * 48 + o0 + j) * 64 + pb] = v;
  }
}

// ---------------- K2: fused stats-finish + BN+ReLU -> span conv -> involution
// grid 3072 = b(16) x g(12) x tile(16: 8x8 spatial), block 256.
__global__ __launch_bounds__(256) void k_invol(
    const float* __restrict__ x, const float* __restrict__ red,
    const float* __restrict__ spart, const float* __restrict__ gamma_s,
    const float* __restrict__ beta_s, const float* __restrict__ Ws,
    float* __restrict__ flat)
{
  __shared__ __align__(16) float xt[196 * 20];   // [s=14*14][c padded 16->20]
  __shared__ __align__(16) float redn[64 * 52];  // [p][o] stride 52 (16B-aligned rows)
  __shared__ __align__(16) float kt[49 * 64];    // [k][p]
  __shared__ float sstats[96];

  int bx = blockIdx.x;
  int tile = bx & 15;
  int g = (bx >> 4) % 12;
  int b = bx / 192;
  int th = (tile >> 2) * 8, tw = (tile & 3) * 8;
  int t = threadIdx.x;

  // finish BN stats from partials (redundant per block, cheap)
  if (t < 96) {
    const v4f* p = (const v4f*)(spart + (size_t)t * 64);
    v4f s4 = p[0];
#pragma unroll
    for (int i = 1; i < 16; ++i) s4 += p[i];
    sstats[t] = s4.x + s4.y + s4.z + s4.w;
  }

  // stage x tile (16 c x 14x14 window, zero-padded), transposed store
  for (int idx = t; idx < 16 * 196; idx += 256) {
    int c = idx / 196, s = idx - c * 196;
    int r = s / 14, q = s - r * 14;
    int sh = th + r - 3, sw = tw + q - 3;
    float v = 0.f;
    if (sh >= 0 && sh < 32 && sw >= 0 && sw < 32)
      v = x[(((size_t)b * 192 + g * 16 + c) << 10) + (sh << 5) + sw];
    xt[s * 20 + c] = v;
  }
  __syncthreads();

  // stage normalized+ReLU'd red for the 64 tile pixels
  for (int idx = t; idx < 64 * 48; idx += 256) {
    int p = idx & 63, o = idx >> 6;
    int py = p >> 3, px = p & 7;
    float mean = sstats[o] * (1.f / 16384.f);
    float var = fmaf(-mean, mean, sstats[48 + o] * (1.f / 16384.f));
    float sc = gamma_s[o] * rsqrtf(var + EPS);
    float sh_ = fmaf(-mean, sc, beta_s[o]);
    float v = red[(size_t)o * 16384 + (b << 10) + ((th + py) << 5) + (tw + px)];
    redn[p * 52 + o] = fmaxf(fmaf(v, sc, sh_), 0.f);
  }
  __syncthreads();

  // span conv: kt[k][p] = sum_o Ws[(g*49+k)*48+o] * redn[p][o]   (b128 redn reads)
  {
    int p = t & 63;
    int kg = __builtin_amdgcn_readfirstlane(t >> 6);  // wave-uniform
    int k0 = kg * 13;
    float acc[13];
#pragma unroll
    for (int j = 0; j < 13; ++j) acc[j] = 0.f;
    const float* wsp = Ws + (size_t)(g * 49 + k0) * 48;
    for (int o4 = 0; o4 < 48; o4 += 4) {
      v4f rv = *(const v4f*)&redn[p * 52 + o4];
#pragma unroll
      for (int j = 0; j < 13; ++j)
        if (k0 + j < 49) {
          acc[j] = fmaf(rv.x, wsp[j * 48 + o4 + 0], acc[j]);
          acc[j] = fmaf(rv.y, wsp[j * 48 + o4 + 1], acc[j]);
          acc[j] = fmaf(rv.z, wsp[j * 48 + o4 + 2], acc[j]);
          acc[j] = fmaf(rv.w, wsp[j * 48 + o4 + 3], acc[j]);
        }
    }
#pragma unroll
    for (int j = 0; j < 13; ++j)
      if (k0 + j < 49) kt[(k0 + j) * 64 + p] = acc[j];
  }
  __syncthreads();

  // involution: out[c0..c0+3][p] = sum_k kt[k][p] * xt[(py+dh)*14+px+dw][c]
  {
    int p = t & 63, cq = t >> 6;
    int c0 = cq * 4;
    int py = p >> 3, px = p & 7;
    float a0 = 0.f, a1 = 0.f, a2 = 0.f, a3 = 0.f;
#pragma unroll
    for (int k = 0; k < 49; ++k) {
      int dh = k / 7, dw = k - dh * 7;
      float kv = kt[k * 64 + p];
      const v4f xv = *(const v4f*)&xt[((py + dh) * 14 + px + dw) * 20 + c0];
      a0 = fmaf(kv, xv.x, a0);
      a1 = fmaf(kv, xv.y, a1);
      a2 = fmaf(kv, xv.z, a2);
      a3 = fmaf(kv, xv.w, a3);
    }
    size_t base = (((size_t)b * 192 + g * 16 + c0) << 10) + ((th + py) << 5) + (tw + px);
    flat[base] = a0;
    flat[base + 1024] = a1;
    flat[base + 2048] = a2;
    flat[base + 3072] = a3;
  }
}

// ---------------- K3: h1part[kc][b][n] = sum_k flat[b][k] * W1[n][k] --------
// grid (8 kc, 128 ntiles of 4 n), block 256. kc-XCD pin kept.
// THE clean vmcnt-stall fix, never yet tested without a confound:
// acc[4][16] (fits default 256-reg cap with f[16]), per phase the 16 flat
// loads are issued FIRST, then the 4 nt W1 prefetches -- consuming f[j]
// waits at worst vmcnt(4) (only the trailing wn stay in flight), and wn is
// consumed next phase (~1024 cyc >= 900 cyc HBM). No sched_barrier pins
// (m141 lesson), no thread splitting, ping-pong w/wn (no copies).
// Demand: 64 acc + 64 f + 32 w + ~16 addr ~= 180 VGPR -> no spill.
__global__ __launch_bounds__(256) void k_gemm1(
    const float* __restrict__ flat, const float* __restrict__ W1,
    float* __restrict__ h1part)
{
  int kc = blockIdx.x;        // 0..7
  int n0 = blockIdx.y * 4;    // 0..508
  int t = threadIdx.x;

  const v4f* W1v = (const v4f*)W1;    // row stride 49152 v4f
  const v4f* flatv = (const v4f*)flat;

  float acc[4][16];
#pragma unroll
  for (int n = 0; n < 4; ++n)
#pragma unroll
    for (int b = 0; b < 16; ++b) acc[n][b] = 0.f;

  int kv = kc * 6144 + t;  // v4f index into the 24576-float chunk

  v4f w[4], wn[4], f[16];
#pragma unroll
  for (int n = 0; n < 4; ++n)
    w[n] = __builtin_nontemporal_load(&W1v[(size_t)(n0 + n) * 49152 + kv]);

#define GEMM1_PHASE(CUR, NXT, PRE)                                         \
  {                                                                        \
    _Pragma("unroll")                                                      \
    for (int b = 0; b < 16; ++b)                                           \
      f[b] = flatv[(size_t)b * 49152 + kv];                                \
    if (PRE) {                                                             \
      _Pragma("unroll")                                                    \
      for (int n = 0; n < 4; ++n)                                          \
        NXT[n] = __builtin_nontemporal_load(                               \
            &W1v[(size_t)(n0 + n) * 49152 + kv + 256]);                    \
    }                                                                      \
    _Pragma("unroll")                                                      \
    for (int b = 0; b < 16; ++b)                                           \
      _Pragma("unroll")                                                    \
      for (int n = 0; n < 4; ++n) {                                        \
        acc[n][b] = fmaf(CUR[n].x, f[b].x, acc[n][b]);                     \
        acc[n][b] = fmaf(CUR[n].y, f[b].y, acc[n][b]);                     \
        acc[n][b] = fmaf(CUR[n].z, f[b].z, acc[n][b]);                     \
        acc[n][b] = fmaf(CUR[n].w, f[b].w, acc[n][b]);                     \
      }                                                                    \
    kv += 256;                                                             \
  }

#pragma unroll 1
  for (int it = 0; it < 12; ++it) {
    GEMM1_PHASE(w, wn, true)            // compute w, prefetch wn
    GEMM1_PHASE(wn, w, (it < 11))       // compute wn, prefetch w
  }
#undef GEMM1_PHASE

  // block reduction: 2 passes of 32 (n,b)-columns via padded LDS transpose,
  // then combine the 8 per-lane partials with shfl (lanes 8v..8v+7).
  __shared__ float rbuf[256 * 33];
#pragma unroll
  for (int pass = 0; pass < 2; ++pass) {
    __syncthreads();
#pragma unroll
    for (int nn = 0; nn < 2; ++nn)
#pragma unroll
      for (int b = 0; b < 16; ++b)
        rbuf[t * 33 + nn * 16 + b] = acc[pass * 2 + nn][b];
    __syncthreads();
    int v = t >> 3, i = t & 7;  // v: column 0..31, i: row-partition 0..7
    float s = 0.f;
#pragma unroll
    for (int j = 0; j < 32; ++j)
      s += rbuf[(i + (j << 3)) * 33 + v];
    s += __shfl_down(s, 4, 8);
    s += __shfl_down(s, 2, 8);
    s += __shfl_down(s, 1, 8);
    if (i == 0) {
      int nn = v >> 4, b = v & 15;
      h1part[(size_t)kc * 8192 + b * 512 + n0 + pass * 2 + nn] = s;
    }
  }
}

// ---------------- K4: fused partial-sum + BN1 + ReLU + gemm2 ----------------
// 8 blocks x 256 (rest5-verified version).
__global__ __launch_bounds__(256) void k_gemm2(
    const float* __restrict__ h1part, const float* __restrict__ g1,
    const float* __restrict__ beta1, const float* __restrict__ W2,
    float* __restrict__ h2pre)
{
  __shared__ __align__(16) float h1s[2][512];
  int t = threadIdx.x;
  int b0 = blockIdx.x * 2;

#pragma unroll
  for (int rep = 0; rep < 2; ++rep) {
    int n = rep * 256 + t;  // 0..511
    float v[16];
#pragma unroll
    for (int b = 0; b < 16; ++b) v[b] = 0.f;
    for (int y = 0; y < 8; ++y)
#pragma unroll
      for (int b = 0; b < 16; ++b)
        v[b] += h1part[(size_t)y * 8192 + b * 512 + n];
    float s = 0.f;
#pragma unroll
    for (int b = 0; b < 16; ++b) s += v[b];
    float mean = s * (1.f / 16.f);
    float q = 0.f;
#pragma unroll
    for (int b = 0; b < 16; ++b) { float d = v[b] - mean; q = fmaf(d, d, q); }
    float inv = rsqrtf(q * (1.f / 16.f) + EPS);
    float sc = g1[n] * inv, sh = beta1[n];
    h1s[0][n] = fmaxf(fmaf(v[b0] - mean, sc, sh), 0.f);
    h1s[1][n] = fmaxf(fmaf(v[b0 + 1] - mean, sc, sh), 0.f);
  }
  __syncthreads();

  int m = t & 127, bsel = t >> 7;
  const v4f* W2v = (const v4f*)W2;  // row stride 128 v4f
  v4f sa = {0.f, 0.f, 0.f, 0.f};
  for (int nv = 0; nv < 128; ++nv) {
    v4f wv = W2v[(size_t)m * 128 + nv];
    v4f hv = *(const v4f*)&h1s[bsel][nv * 4];
    sa.x = fmaf(hv.x, wv.x, sa.x);
    sa.y = fmaf(hv.y, wv.y, sa.y);
    sa.z = fmaf(hv.z, wv.z, sa.z);
    sa.w = fmaf(hv.w, wv.w, sa.w);
  }
  h2pre[(b0 + bsel) * 128 + m] = (sa.x + sa.y) + (sa.z + sa.w);
}

// ---------------- K5: BN2+ReLU then out = h2 @ W3^T + b3 ----------------
__global__ __launch_bounds__(320) void k_tail(
    const float* __restrict__ h2pre, const float* __restrict__ g2,
    const float* __restrict__ beta2, const float* __restrict__ W3,
    const float* __restrict__ b3, float* __restrict__ out)
{
  __shared__ float h2[16 * 128];
  int t = threadIdx.x;
  if (t < 128) {
    float v[16];
    float s = 0.f;
#pragma unroll
    for (int b = 0; b < 16; ++b) { v[b] = h2pre[b * 128 + t]; s += v[b]; }
    float mean = s * (1.f / 16.f);
    float q = 0.f;
#pragma unroll
    for (int b = 0; b < 16; ++b) { float d = v[b] - mean; q = fmaf(d, d, q); }
    float inv = rsqrtf(q * (1.f / 16.f) + EPS);
    float sc = g2[t] * inv, sh = beta2[t];
#pragma unroll
    for (int b = 0; b < 16; ++b)
      h2[b * 128 + t] = fmaxf(fmaf(v[b] - mean, sc, sh), 0.f);
  }
  __syncthreads();
  if (t < 272) {
    int b = t / 17, j = t - b * 17;
    float s = b3[j];
    const float* hp = h2 + b * 128;
    const float* wp = W3 + j * 128;
#pragma unroll 4
    for (int m = 0; m < 128; ++m) s = fmaf(hp[m], wp[m], s);
    out[t] = s;
  }
}

extern "C" void kernel_launch(void* const* d_in, const int* in_sizes, int n_in,
                              void* d_out, int out_size, void* d_ws, size_t ws_size,
                              hipStream_t stream)
{
  const float* x       = (const float*)d_in[0];
  const float* Wr      = (const float*)d_in[1];
  const float* gamma_s = (const float*)d_in[2];
  const float* beta_s  = (const float*)d_in[3];
  const float* Ws      = (const float*)d_in[4];
  const float* W1      = (const float*)d_in[5];
  // d_in[6] = b1: cancels under train-mode BN (mean subtraction)
  const float* g1      = (const float*)d_in[7];
  const float* beta1   = (const float*)d_in[8];
  const float* W2      = (const float*)d_in[9];
  // d_in[10] = b2: cancels under train-mode BN
  const float* g2      = (const float*)d_in[11];
  const float* beta2   = (const float*)d_in[12];
  const float* W3      = (const float*)d_in[13];
  const float* b3      = (const float*)d_in[14];

  float* ws = (float*)d_ws;
  float* red    = ws;                     // 48*16384      = 786432
  float* flat   = red + 786432;           // 16*192*1024   = 3145728
  float* spart  = flat + 3145728;         // 2*48*64       = 6144
  float* h1part = spart + 6144;           // 8*16*512      = 65536
  float* h2pre  = h1part + 65536;         // 2048

  k_reduce_conv<<<512, 256, 0, stream>>>(x, Wr, red, spart);
  k_invol<<<3072, 256, 0, stream>>>(x, red, spart, gamma_s, beta_s, Ws, flat);
  k_gemm1<<<dim3(8, 128), 256, 0, stream>>>(flat, W1, h1part);
  k_gemm2<<<8, 256, 0, stream>>>(h1part, g1, beta1, W2, h2pre);
  k_tail<<<1, 320, 0, stream>>>(h2pre, g2, beta2, W3, b3, (float*)d_out);
}

// Round 13
// 274.804 us; speedup vs baseline: 1.0982x; 1.0982x over previous
//
#include <hip/hip_runtime.h>

#define EPS 1e-5f

typedef float v4f __attribute__((ext_vector_type(4)));

// ---------------- K1: red[o][pix] = sum_c x[b,c,hw] * Wr[o,c]  (+ stats partials)
// grid 512 = 8 oGroups(6 o each) x 64 pixBlocks, block 256
__global__ __launch_bounds__(256) void k_reduce_conv(
    const float* __restrict__ x, const float* __restrict__ Wr,
    float* __restrict__ red, float* __restrict__ spart)
{
  int ob = blockIdx.x >> 6;           // 0..7
  int pb = blockIdx.x & 63;           // 0..63
  int o0 = ob * 6;
  int pix = (pb << 8) + threadIdx.x;  // 0..16383
  int b = pix >> 10;
  int hw = pix & 1023;
  const float* xp = x + ((size_t)b * 192) * 1024 + hw;
  float acc[6] = {0.f, 0.f, 0.f, 0.f, 0.f, 0.f};
  for (int c = 0; c < 192; ++c) {
    float xv = xp[(size_t)c * 1024];
#pragma unroll
    for (int j = 0; j < 6; ++j)
      acc[j] = fmaf(xv, Wr[(o0 + j) * 192 + c], acc[j]);
  }
#pragma unroll
  for (int j = 0; j < 6; ++j)
    red[(size_t)(o0 + j) * 16384 + pix] = acc[j];

  // per-block sum / sumsq partials for BN stats
  int t = threadIdx.x, lane = t & 63, wid = t >> 6;
  float sv[6], qv[6];
#pragma unroll
  for (int j = 0; j < 6; ++j) { sv[j] = acc[j]; qv[j] = acc[j] * acc[j]; }
#pragma unroll
  for (int off = 32; off > 0; off >>= 1)
#pragma unroll
    for (int j = 0; j < 6; ++j) {
      sv[j] += __shfl_down(sv[j], off);
      qv[j] += __shfl_down(qv[j], off);
    }
  __shared__ float ps[4][12];
  if (lane == 0)
#pragma unroll
    for (int j = 0; j < 6; ++j) { ps[wid][j] = sv[j]; ps[wid][6 + j] = qv[j]; }
  __syncthreads();
  if (t < 12) {
    float v = ps[0][t] + ps[1][t] + ps[2][t] + ps[3][t];
    int j = t % 6, s = t / 6;
    spart[(size_t)(s * 48 + o0 + j) * 64 + pb] = v;
  }
}

// ---------------- K2: fused stats-finish + BN+ReLU -> span conv -> involution
// grid 3072 = b(16) x g(12) x tile(16: 8x8 spatial), block 256.
__global__ __launch_bounds__(256) void k_invol(
    const float* __restrict__ x, const float* __restrict__ red,
    const float* __restrict__ spart, const float* __restrict__ gamma_s,
    const float* __restrict__ beta_s, const float* __restrict__ Ws,
    float* __restrict__ flat)
{
  __shared__ __align__(16) float xt[196 * 20];   // [s=14*14][c padded 16->20]
  __shared__ __align__(16) float redn[64 * 52];  // [p][o] stride 52 (16B-aligned rows)
  __shared__ __align__(16) float kt[49 * 64];    // [k][p]
  __shared__ float sstats[96];

  int bx = blockIdx.x;
  int tile = bx & 15;
  int g = (bx >> 4) % 12;
  int b = bx / 192;
  int th = (tile >> 2) * 8, tw = (tile & 3) * 8;
  int t = threadIdx.x;

  // finish BN stats from partials (redundant per block, cheap)
  if (t < 96) {
    const v4f* p = (const v4f*)(spart + (size_t)t * 64);
    v4f s4 = p[0];
#pragma unroll
    for (int i = 1; i < 16; ++i) s4 += p[i];
    sstats[t] = s4.x + s4.y + s4.z + s4.w;
  }

  // stage x tile (16 c x 14x14 window, zero-padded), transposed store
  for (int idx = t; idx < 16 * 196; idx += 256) {
    int c = idx / 196, s = idx - c * 196;
    int r = s / 14, q = s - r * 14;
    int sh = th + r - 3, sw = tw + q - 3;
    float v = 0.f;
    if (sh >= 0 && sh < 32 && sw >= 0 && sw < 32)
      v = x[(((size_t)b * 192 + g * 16 + c) << 10) + (sh << 5) + sw];
    xt[s * 20 + c] = v;
  }
  __syncthreads();

  // stage normalized+ReLU'd red for the 64 tile pixels
  for (int idx = t; idx < 64 * 48; idx += 256) {
    int p = idx & 63, o = idx >> 6;
    int py = p >> 3, px = p & 7;
    float mean = sstats[o] * (1.f / 16384.f);
    float var = fmaf(-mean, mean, sstats[48 + o] * (1.f / 16384.f));
    float sc = gamma_s[o] * rsqrtf(var + EPS);
    float sh_ = fmaf(-mean, sc, beta_s[o]);
    float v = red[(size_t)o * 16384 + (b << 10) + ((th + py) << 5) + (tw + px)];
    redn[p * 52 + o] = fmaxf(fmaf(v, sc, sh_), 0.f);
  }
  __syncthreads();

  // span conv: kt[k][p] = sum_o Ws[(g*49+k)*48+o] * redn[p][o]   (b128 redn reads)
  {
    int p = t & 63;
    int kg = __builtin_amdgcn_readfirstlane(t >> 6);  // wave-uniform
    int k0 = kg * 13;
    float acc[13];
#pragma unroll
    for (int j = 0; j < 13; ++j) acc[j] = 0.f;
    const float* wsp = Ws + (size_t)(g * 49 + k0) * 48;
    for (int o4 = 0; o4 < 48; o4 += 4) {
      v4f rv = *(const v4f*)&redn[p * 52 + o4];
#pragma unroll
      for (int j = 0; j < 13; ++j)
        if (k0 + j < 49) {
          acc[j] = fmaf(rv.x, wsp[j * 48 + o4 + 0], acc[j]);
          acc[j] = fmaf(rv.y, wsp[j * 48 + o4 + 1], acc[j]);
          acc[j] = fmaf(rv.z, wsp[j * 48 + o4 + 2], acc[j]);
          acc[j] = fmaf(rv.w, wsp[j * 48 + o4 + 3], acc[j]);
        }
    }
#pragma unroll
    for (int j = 0; j < 13; ++j)
      if (k0 + j < 49) kt[(k0 + j) * 64 + p] = acc[j];
  }
  __syncthreads();

  // involution: out[c0..c0+3][p] = sum_k kt[k][p] * xt[(py+dh)*14+px+dw][c]
  {
    int p = t & 63, cq = t >> 6;
    int c0 = cq * 4;
    int py = p >> 3, px = p & 7;
    float a0 = 0.f, a1 = 0.f, a2 = 0.f, a3 = 0.f;
#pragma unroll
    for (int k = 0; k < 49; ++k) {
      int dh = k / 7, dw = k - dh * 7;
      float kv = kt[k * 64 + p];
      const v4f xv = *(const v4f*)&xt[((py + dh) * 14 + px + dw) * 20 + c0];
      a0 = fmaf(kv, xv.x, a0);
      a1 = fmaf(kv, xv.y, a1);
      a2 = fmaf(kv, xv.z, a2);
      a3 = fmaf(kv, xv.w, a3);
    }
    size_t base = (((size_t)b * 192 + g * 16 + c0) << 10) + ((th + py) << 5) + (tw + px);
    flat[base] = a0;
    flat[base + 1024] = a1;
    flat[base + 2048] = a2;
    flat[base + 3072] = a3;
  }
}

// ---------------- K3: h1part[kc][b][n] = sum_k flat[b][k] * W1[n][k] --------
// R3-winner structure (129 us measured) with ONE change: flat chain deepened
// to depth 2 (prefetch b+2). Per b-step the 32 FMAs give 64 cyc cover; at
// depth 2 x 2 waves/SIMD the chain covers ~256 cyc >= ~200 cyc L2 latency,
// removing the standing depth-1 bubble. +8 VGPR (~215 total, under the 256
// default cap). Everything else identical: grid (8 kc, 64 ntiles of 8 n),
// kc-XCD pin, nt W1 register double-buffer, LDS-transpose epilogue.
__global__ __launch_bounds__(256) void k_gemm1(
    const float* __restrict__ flat, const float* __restrict__ W1,
    float* __restrict__ h1part)
{
  int kc = blockIdx.x;        // 0..7
  int n0 = blockIdx.y * 8;    // 0..504
  int t = threadIdx.x;

  const v4f* W1v = (const v4f*)W1;    // row stride 49152 v4f
  const v4f* flatv = (const v4f*)flat;

  float acc[8][16];
#pragma unroll
  for (int n = 0; n < 8; ++n)
#pragma unroll
    for (int b = 0; b < 16; ++b) acc[n][b] = 0.f;

  int kv = kc * 6144 + t;  // v4f index into the 24576-float chunk
  v4f wv[8], wvn[8];
#pragma unroll
  for (int n = 0; n < 8; ++n)
    wv[n] = __builtin_nontemporal_load(&W1v[(size_t)(n0 + n) * 49152 + kv]);

  for (int it = 0; it < 24; ++it) {
    if (it < 23) {
#pragma unroll
      for (int n = 0; n < 8; ++n)
        wvn[n] = __builtin_nontemporal_load(&W1v[(size_t)(n0 + n) * 49152 + kv + 256]);
    }
    v4f f0 = flatv[kv];
    v4f f1 = flatv[(size_t)1 * 49152 + kv];
#pragma unroll
    for (int b = 0; b < 16; ++b) {
      v4f f2;
      if (b < 14) f2 = flatv[(size_t)(b + 2) * 49152 + kv];
#pragma unroll
      for (int n = 0; n < 8; ++n) {
        acc[n][b] = fmaf(wv[n].x, f0.x, acc[n][b]);
        acc[n][b] = fmaf(wv[n].y, f0.y, acc[n][b]);
        acc[n][b] = fmaf(wv[n].z, f0.z, acc[n][b]);
        acc[n][b] = fmaf(wv[n].w, f0.w, acc[n][b]);
      }
      f0 = f1;
      f1 = f2;
    }
    if (it < 23) {
#pragma unroll
      for (int n = 0; n < 8; ++n) wv[n] = wvn[n];
    }
    kv += 256;
  }

  // block reduction: 4 passes of 32 (n,b)-columns via padded LDS transpose,
  // then combine the 8 per-lane partials with shfl (lanes 8v..8v+7).
  __shared__ float rbuf[256 * 33];
#pragma unroll
  for (int pass = 0; pass < 4; ++pass) {
    __syncthreads();
#pragma unroll
    for (int nn = 0; nn < 2; ++nn)
#pragma unroll
      for (int b = 0; b < 16; ++b)
        rbuf[t * 33 + nn * 16 + b] = acc[pass * 2 + nn][b];
    __syncthreads();
    int v = t >> 3, i = t & 7;  // v: column 0..31, i: row-partition 0..7
    float s = 0.f;
#pragma unroll
    for (int j = 0; j < 32; ++j)
      s += rbuf[(i + (j << 3)) * 33 + v];
    s += __shfl_down(s, 4, 8);
    s += __shfl_down(s, 2, 8);
    s += __shfl_down(s, 1, 8);
    if (i == 0) {
      int nn = v >> 4, b = v & 15;
      h1part[(size_t)kc * 8192 + b * 512 + n0 + pass * 2 + nn] = s;
    }
  }
}

// ---------------- K4: fused partial-sum + BN1 + ReLU + gemm2 ----------------
// 8 blocks x 256 (rest5-verified version).
__global__ __launch_bounds__(256) void k_gemm2(
    const float* __restrict__ h1part, const float* __restrict__ g1,
    const float* __restrict__ beta1, const float* __restrict__ W2,
    float* __restrict__ h2pre)
{
  __shared__ __align__(16) float h1s[2][512];
  int t = threadIdx.x;
  int b0 = blockIdx.x * 2;

#pragma unroll
  for (int rep = 0; rep < 2; ++rep) {
    int n = rep * 256 + t;  // 0..511
    float v[16];
#pragma unroll
    for (int b = 0; b < 16; ++b) v[b] = 0.f;
    for (int y = 0; y < 8; ++y)
#pragma unroll
      for (int b = 0; b < 16; ++b)
        v[b] += h1part[(size_t)y * 8192 + b * 512 + n];
    float s = 0.f;
#pragma unroll
    for (int b = 0; b < 16; ++b) s += v[b];
    float mean = s * (1.f / 16.f);
    float q = 0.f;
#pragma unroll
    for (int b = 0; b < 16; ++b) { float d = v[b] - mean; q = fmaf(d, d, q); }
    float inv = rsqrtf(q * (1.f / 16.f) + EPS);
    float sc = g1[n] * inv, sh = beta1[n];
    h1s[0][n] = fmaxf(fmaf(v[b0] - mean, sc, sh), 0.f);
    h1s[1][n] = fmaxf(fmaf(v[b0 + 1] - mean, sc, sh), 0.f);
  }
  __syncthreads();

  int m = t & 127, bsel = t >> 7;
  const v4f* W2v = (const v4f*)W2;  // row stride 128 v4f
  v4f sa = {0.f, 0.f, 0.f, 0.f};
  for (int nv = 0; nv < 128; ++nv) {
    v4f wv = W2v[(size_t)m * 128 + nv];
    v4f hv = *(const v4f*)&h1s[bsel][nv * 4];
    sa.x = fmaf(hv.x, wv.x, sa.x);
    sa.y = fmaf(hv.y, wv.y, sa.y);
    sa.z = fmaf(hv.z, wv.z, sa.z);
    sa.w = fmaf(hv.w, wv.w, sa.w);
  }
  h2pre[(b0 + bsel) * 128 + m] = (sa.x + sa.y) + (sa.z + sa.w);
}

// ---------------- K5: BN2+ReLU then out = h2 @ W3^T + b3 ----------------
__global__ __launch_bounds__(320) void k_tail(
    const float* __restrict__ h2pre, const float* __restrict__ g2,
    const float* __restrict__ beta2, const float* __restrict__ W3,
    const float* __restrict__ b3, float* __restrict__ out)
{
  __shared__ float h2[16 * 128];
  int t = threadIdx.x;
  if (t < 128) {
    float v[16];
    float s = 0.f;
#pragma unroll
    for (int b = 0; b < 16; ++b) { v[b] = h2pre[b * 128 + t]; s += v[b]; }
    float mean = s * (1.f / 16.f);
    float q = 0.f;
#pragma unroll
    for (int b = 0; b < 16; ++b) { float d = v[b] - mean; q = fmaf(d, d, q); }
    float inv = rsqrtf(q * (1.f / 16.f) + EPS);
    float sc = g2[t] * inv, sh = beta2[t];
#pragma unroll
    for (int b = 0; b < 16; ++b)
      h2[b * 128 + t] = fmaxf(fmaf(v[b] - mean, sc, sh), 0.f);
  }
  __syncthreads();
  if (t < 272) {
    int b = t / 17, j = t - b * 17;
    float s = b3[j];
    const float* hp = h2 + b * 128;
    const float* wp = W3 + j * 128;
#pragma unroll 4
    for (int m = 0; m < 128; ++m) s = fmaf(hp[m], wp[m], s);
    out[t] = s;
  }
}

extern "C" void kernel_launch(void* const* d_in, const int* in_sizes, int n_in,
                              void* d_out, int out_size, void* d_ws, size_t ws_size,
                              hipStream_t stream)
{
  const float* x       = (const float*)d_in[0];
  const float* Wr      = (const float*)d_in[1];
  const float* gamma_s = (const float*)d_in[2];
  const float* beta_s  = (const float*)d_in[3];
  const float* Ws      = (const float*)d_in[4];
  const float* W1      = (const float*)d_in[5];
  // d_in[6] = b1: cancels under train-mode BN (mean subtraction)
  const float* g1      = (const float*)d_in[7];
  const float* beta1   = (const float*)d_in[8];
  const float* W2      = (const float*)d_in[9];
  // d_in[10] = b2: cancels under train-mode BN
  const float* g2      = (const float*)d_in[11];
  const float* beta2   = (const float*)d_in[12];
  const float* W3      = (const float*)d_in[13];
  const float* b3      = (const float*)d_in[14];

  float* ws = (float*)d_ws;
  float* red    = ws;                     // 48*16384      = 786432
  float* flat   = red + 786432;           // 16*192*1024   = 3145728
  float* spart  = flat + 3145728;         // 2*48*64       = 6144
  float* h1part = spart + 6144;           // 8*16*512      = 65536
  float* h2pre  = h1part + 65536;         // 2048

  k_reduce_conv<<<512, 256, 0, stream>>>(x, Wr, red, spart);
  k_invol<<<3072, 256, 0, stream>>>(x, red, spart, gamma_s, beta_s, Ws, flat);
  k_gemm1<<<dim3(8, 64), 256, 0, stream>>>(flat, W1, h1part);
  k_gemm2<<<8, 256, 0, stream>>>(h1part, g1, beta1, W2, h2pre);
  k_tail<<<1, 320, 0, stream>>>(h2pre, g2, beta2, W3, b3, (float*)d_out);
}